// Round 4
// baseline (212.031 us; speedup 1.0000x reference)
//
#include <hip/hip_runtime.h>
#include <stdint.h>

#define N_ANCH 36864
#define KCAND  4096
#define NBUCK  384
#define NSEL   300
#define NGT    64
#define NBATCH 16
#define SCORE_THRESH 0.908f
#define TESTW0 9          // tester waves are wv 9..15 (7 waves x 64 slots = 448 >= NSEL)

typedef unsigned long long u64;

__device__ __forceinline__ float clip01(float v) { return fminf(fmaxf(v, 0.0f), 1.0f); }

// Exact decision "RN(inter/D) >= 0.5f" without division in the common case.
// D is computed in the reference's exact op order: ((aa+ab) - inter) + 1e-7f.
// Proof: q = RN(inter/D) >= 0.5  <=>  inter/D >= 0.5 - 2^-26 (tie rounds up to
// 0.5, which has an even mantissa).
//   hi:  inter >= 0.5*D (exact product)  =>  inter/D >= 0.5      => q >= 0.5.
//   lo:  r = RN(dt*(1-2^-23)) <= dt*(1-2^-24) < D*(0.5-2^-26);
//        inter < r  =>  inter/D < 0.5 - 2^-26  =>  q < 0.5.
// Band [r, dt): fall back to the actual IEEE division (prob ~2^-23 per pair).
__device__ __forceinline__ bool supp_pair(float ax, float ay, float az, float aw, float aa,
                                          const float4 B, float ab) {
    float y1 = fmaxf(ax, B.x);
    float x1 = fmaxf(ay, B.y);
    float y2 = fminf(az, B.z);
    float x2 = fminf(aw, B.w);
    float ih = fmaxf(y2 - y1, 0.0f);
    float iw = fmaxf(x2 - x1, 0.0f);
    float inter = ih * iw;
    float D  = ((aa + ab) - inter) + 1e-7f;   // exact reference op order
    float dt = 0.5f * D;                      // exact (no subnormals: D >= 1e-7)
    float r  = fmaf(dt, -0x1p-23f, dt);
    bool hi  = inter >= dt;                   // definitely q >= 0.5
    bool unc = (!hi) && (inter >= r);         // boundary band -> divide
    if (__builtin_expect(__any((int)unc), 0))
        return (inter / D) >= 0.5f;           // exact for every lane
    return hi;
}

__device__ __forceinline__ float4 decode_one(const float4 a4, const float4 d4) {
    float ah = a4.z - a4.x, aw = a4.w - a4.y;
    float acy = a4.x + 0.5f * ah, acx = a4.y + 0.5f * aw;
    float h = expf(d4.z) * ah, w = expf(d4.w) * aw;
    float cy = d4.x * ah + acy, cx = d4.y * aw + acx;
    float y1 = cy - 0.5f * h, x1 = cx - 0.5f * w;
    return make_float4(y1, x1, y1 + h, x1 + w);
}

// scores in (0.908, 1.0) all share exponent 0x7E -> ulp-linear bucket digit,
// ascending digit == descending score. width 4096 ulps -> lambda ~9 per bucket.
__device__ __forceinline__ int bucket_of(float s) {
    unsigned d = (0x3F800000u - __float_as_uint(s)) >> 12;
    return (d < NBUCK) ? (int)d : (NBUCK - 1);
}

__global__ __launch_bounds__(1024)
void roi_bbox_kernel(const float* __restrict__ deltas,
                     const float* __restrict__ labels,
                     const float* __restrict__ anchors,
                     const float* __restrict__ gt,
                     float* __restrict__ out)
{
    __shared__ u64    s_sorted[KCAND];   // 32 KB, bucket-ordered then rank-sorted
    __shared__ int    s_hist[NBUCK];
    __shared__ int    s_cur[NBUCK];
    __shared__ int    s_base[NBUCK + 1];
    __shared__ float4 s_accB[NSEL + 4];  // accepted raw (unclipped) boxes, pop order
    __shared__ float4 s_clsB[3][NSEL + 4];   // class-segregated accepted boxes
    __shared__ float  s_clsA[3][NSEL + 4];   // their areas
    __shared__ int    s_clsN[3];
    __shared__ float4 s_cbox[2][64];     // double-buffered chunk boxes
    __shared__ unsigned int s_pre[2][64];    // double-buffered suppression flags
    __shared__ unsigned int s_gmlo[2][64];
    __shared__ unsigned int s_gmhi[2][64];
    __shared__ int   s_accCount;
    __shared__ float s_merged[NSEL];
    __shared__ int   s_gtbest[NSEL];
    __shared__ float4 s_gt[NGT];
    __shared__ int   s_selidx[64];

    const int b    = blockIdx.x;
    const int tid  = threadIdx.x;
    const int lane = tid & 63;
    const int wv   = tid >> 6;
    const float*  sc    = labels + (size_t)b * N_ANCH;
    const float4* sc4   = (const float4*)sc;
    const float4* anch4 = (const float4*)(anchors + (size_t)b * N_ANCH * 4);
    const float4* del4  = (const float4*)(deltas  + (size_t)b * N_ANCH * 4);
    const float4* gt4   = (const float4*)(gt + (size_t)b * NGT * 4);

    if (tid < NBUCK) s_hist[tid] = 0;
    if (tid < 3) s_clsN[tid] = 0;
    if (tid == 0) s_accCount = 0;
    __syncthreads();

    // ---- Phase A1: bucket histogram (float4-vectorized) ----
    for (int i = tid; i < N_ANCH / 4; i += 1024) {
        float4 v = sc4[i];
        float vv[4] = {v.x, v.y, v.z, v.w};
        #pragma unroll
        for (int k = 0; k < 4; ++k)
            if (vv[k] > SCORE_THRESH) atomicAdd(&s_hist[bucket_of(vv[k])], 1);
    }
    __syncthreads();

    // ---- exclusive scan of 384 counts (wave 0: 6 counts/lane + shfl scan) ----
    if (tid < 64) {
        int c[6]; int sum = 0;
        #pragma unroll
        for (int k = 0; k < 6; ++k) { c[k] = s_hist[tid * 6 + k]; sum += c[k]; }
        int inc = sum;
        #pragma unroll
        for (int off = 1; off < 64; off <<= 1) {
            int v = __shfl_up(inc, off);
            if (lane >= off) inc += v;
        }
        int excl = inc - sum;
        #pragma unroll
        for (int k = 0; k < 6; ++k) {
            s_base[tid * 6 + k] = excl;
            s_cur[tid * 6 + k]  = excl;
            excl += c[k];
        }
        if (tid == 63) s_base[NBUCK] = excl;
    }
    __syncthreads();

    // ---- Phase A2: scatter keys into bucket regions (L2-hot reload, vectorized) ----
    for (int i = tid; i < N_ANCH / 4; i += 1024) {
        float4 v = sc4[i];
        float vv[4] = {v.x, v.y, v.z, v.w};
        #pragma unroll
        for (int k = 0; k < 4; ++k) {
            float sval = vv[k];
            if (sval > SCORE_THRESH) {
                int idx = i * 4 + k;
                int pos = atomicAdd(&s_cur[bucket_of(sval)], 1);
                if (pos < KCAND)
                    s_sorted[pos] = ((u64)__float_as_uint(sval) << 32)
                                  | (u64)(0xFFFFFFFFu - (unsigned)idx);
            }
        }
    }
    __syncthreads();

    // ---- per-bucket rank sort (one wave per bucket, no barriers inside) ----
    for (int bk = wv; bk < NBUCK; bk += 16) {
        int lo = s_base[bk], hi = s_base[bk + 1];
        if (lo > KCAND) lo = KCAND;
        if (hi > KCAND) hi = KCAND;
        int n = hi - lo;
        if (n <= 1) continue;
        u64 mykey = (lane < n) ? s_sorted[lo + lane] : 0ull;
        int rank = 0;
        for (int j = 0; j < n; ++j) {          // broadcast reads, conflict-free
            u64 kj = s_sorted[lo + j];
            rank += (kj > mykey);
        }
        if (lane < n) s_sorted[lo + rank] = mykey;  // in-wave: reads precede write
    }
    __syncthreads();

    int M = s_base[NBUCK]; if (M > KCAND) M = KCAND;

    // decode chunk 0, zero both mask-buffer sets
    if (tid < 64) {
        s_pre[0][tid] = 0u; s_gmlo[0][tid] = 0u; s_gmhi[0][tid] = 0u;
        s_pre[1][tid] = 0u; s_gmlo[1][tid] = 0u; s_gmhi[1][tid] = 0u;
        if (tid < M) {
            u64 key = s_sorted[tid];
            int idx = (int)(0xFFFFFFFFu - (unsigned)(key & 0xFFFFFFFFull));
            s_cbox[0][tid] = decode_one(anch4[idx], del4[idx]);
        }
    }
    __syncthreads();

    // ---- Phase B: greedy NMS over sorted candidates, 64-wide chunks ----
    int accCount = 0;
    for (int start = 0; start < M && accCount < NSEL; start += 64) {
        int C = M - start; if (C > 64) C = 64;
        int buf = (start >> 6) & 1;
        int c = tid & 63;

        if (wv == 1) {
            // zero next chunk's mask buffers (consumed only after resolve barrier)
            s_pre[buf ^ 1][c]  = 0u;
            s_gmlo[buf ^ 1][c] = 0u;
            s_gmhi[buf ^ 1][c] = 0u;
            int ni = start + 64 + c;           // prefetch-decode next chunk
            if (ni < M) {
                u64 key = s_sorted[ni];
                int idx = (int)(0xFFFFFFFFu - (unsigned)(key & 0xFFFFFFFFull));
                s_cbox[buf ^ 1][c] = decode_one(anch4[idx], del4[idx]);
            }
        } else if (wv >= TESTW0) {
            // ---- tester waves: lane = accepted box (flipped loop) ----
            // Window t covers slots [64t, 64t+64) of the concatenated class
            // lists. Class lists are area-coherent, so the window's [mn,mx]
            // area range is tight -> the 2x-area interval filter (necessary
            // condition for IoU>=0.5) rejects ~2/3 of candidate pairings.
            // Correctness never depends on the classing: the interval test is
            // conservative (2.001 margin swallows all f32 rounding).
            int t = wv - TESTW0;
            int n0 = s_clsN[0], n1 = s_clsN[1], n2 = s_clsN[2];
            int g = t * 64 + lane;
            float4 A = make_float4(0.f, 0.f, 0.f, 0.f);   // empty: inter==0, never suppresses
            float Aa = 0.f;
            if (g < n0)                  { A = s_clsB[0][g];           Aa = s_clsA[0][g]; }
            else if (g < n0 + n1)        { A = s_clsB[1][g - n0];      Aa = s_clsA[1][g - n0]; }
            else if (g < n0 + n1 + n2)   { A = s_clsB[2][g - n0 - n1]; Aa = s_clsA[2][g - n0 - n1]; }
            float mn = (Aa > 0.f) ? Aa : 1e30f;
            float mx = Aa;
            #pragma unroll
            for (int off = 1; off < 64; off <<= 1) {
                mn = fminf(mn, __shfl_xor(mn, off));
                mx = fmaxf(mx, __shfl_xor(mx, off));
            }
            // ballot of candidates whose area can interact with this window
            float4 cbl = s_cbox[buf][lane];
            float cba = (cbl.z - cbl.x) * (cbl.w - cbl.y);
            bool match = (fmaf(cba, 2.001f, 1e-6f) >= mn) &&
                         (cba <= fmaf(mx, 2.001f, 1e-6f));
            u64 m = __ballot((int)match);
            if (C < 64) m &= ((1ull << C) - 1ull);
            while (m) {
                int cc = __builtin_ctzll(m); m &= m - 1;
                if (s_pre[buf][cc]) continue;            // early skip (race-benign)
                float4 bc = s_cbox[buf][cc];             // broadcast read
                float ab = (bc.z - bc.x) * (bc.w - bc.y);
                bool s = supp_pair(A.x, A.y, A.z, A.w, Aa, bc, ab);
                if (__any((int)s)) { if (lane == 0) s_pre[buf][cc] = 1u; }
            }
        } else if (c < C) {
            // intra-chunk tests: 8 slices over waves {0,2..8}
            int sidx = (wv == 0) ? 0 : (wv - 1);
            float4 bc = s_cbox[buf][c];
            float  ba = (bc.z - bc.x) * (bc.w - bc.y);
            unsigned mlo = 0u, mhi = 0u;
            for (int j = sidx; j < c; j += 8) {
                float4 bj = s_cbox[buf][j];
                float  aj = (bj.z - bj.x) * (bj.w - bj.y);
                if (supp_pair(bj.x, bj.y, bj.z, bj.w, aj, bc, ba)) {
                    if (j < 32) mlo |= 1u << j; else mhi |= 1u << (j - 32);
                }
            }
            if (mlo) atomicOr(&s_gmlo[buf][c], mlo);
            if (mhi) atomicOr(&s_gmhi[buf][c], mhi);
        }
        __syncthreads();

        // wave-0 resolution: iterate only over alive lanes (each pick == accept)
        if (tid < 64) {
            u64 mymask = ((u64)s_gmhi[buf][tid] << 32) | (u64)s_gmlo[buf][tid];
            bool alive = (tid < C) && (s_pre[buf][tid] == 0u);
            u64 accbits = 0ull;
            u64 done = 0ull;
            int room = NSEL - accCount;
            int na = 0;
            while (na < room) {
                u64 am  = __ballot(alive);
                u64 rem = am & ~done;
                if (!rem) break;
                int l = __ffsll(rem) - 1;
                done = (2ull << l) - 1ull;
                accbits |= (1ull << l);
                ++na;
                if ((mymask >> l) & 1ull) alive = false;
            }
            // pop-order output list + class-segregated test lists
            bool acc = (accbits >> tid) & 1ull;
            float4 bx = make_float4(0.f, 0.f, 0.f, 0.f);
            float a = 0.f; int q = 3;
            if (acc) {
                bx = s_cbox[buf][tid];
                a  = (bx.z - bx.x) * (bx.w - bx.y);
                q  = (a < 0.03f) ? 0 : ((a < 0.13f) ? 1 : 2);
                int rank = __popcll(accbits & ((1ull << tid) - 1ull));
                s_accB[accCount + rank] = bx;
            }
            u64 m0 = __ballot((int)(q == 0));
            u64 m1 = __ballot((int)(q == 1));
            u64 m2 = __ballot((int)(q == 2));
            if (acc) {
                u64 mq = (q == 0) ? m0 : ((q == 1) ? m1 : m2);
                int pos = s_clsN[q] + __popcll(mq & ((1ull << tid) - 1ull));
                s_clsB[q][pos] = bx;
                s_clsA[q][pos] = a;
            }
            if (tid == 0) {
                s_clsN[0] += __popcll(m0);
                s_clsN[1] += __popcll(m1);
                s_clsN[2] += __popcll(m2);
                s_accCount = accCount + __popcll(accbits);
            }
        }
        __syncthreads();
        accCount = s_accCount;
    }

    // ---- Phase C: select_rois ----
    if (tid < NGT) s_gt[tid] = gt4[tid];
    __syncthreads();

    if (tid < NSEL) {
        float4 bx;
        if (tid < accCount) {
            float4 r = s_accB[tid];
            bx = make_float4(clip01(r.x), clip01(r.y), clip01(r.z), clip01(r.w));
        } else bx = make_float4(0.f, 0.f, 0.f, 0.f);
        float aa = (bx.z - bx.x) * (bx.w - bx.y);
        float best = -1e38f; int bi = 0;
        for (int g = 0; g < NGT; ++g) {
            float4 gb = s_gt[g];
            float y1 = fmaxf(bx.x, gb.x);
            float x1 = fmaxf(bx.y, gb.y);
            float y2 = fminf(bx.z, gb.z);
            float x2 = fminf(bx.w, gb.w);
            float ih = fmaxf(y2 - y1, 0.0f);
            float iw = fmaxf(x2 - x1, 0.0f);
            float inter = ih * iw;
            float ab = (gb.z - gb.x) * (gb.w - gb.y);
            float iou = inter / (aa + ab - inter + 1e-7f);
            if (iou > best) { best = iou; bi = g; }   // first-occurrence argmax
        }
        s_merged[tid] = best;
        s_gtbest[tid] = bi;
    }
    __syncthreads();

    // stable top-64 via rank selection: rank = #{j: v_j > v_i || (v_j==v_i && j<i)}
    if (tid < NSEL) {
        float v = s_merged[tid];
        int rank = 0;
        for (int j = 0; j < NSEL; ++j) {
            float u = s_merged[j];
            rank += (u > v) || (u == v && j < tid);
        }
        if (rank < 64) s_selidx[rank] = tid;
    }
    __syncthreads();

    // ---- outputs ----
    float* outIdx = out + (size_t)NBATCH * 128 * 4;   // 8192 box floats first
    if (tid < 256) {
        int r = tid >> 2, cc = tid & 3;
        int i = s_selidx[r];
        float val = 0.0f;
        if (i < accCount) {
            const float* p = (const float*)&s_accB[i];
            val = clip01(p[cc]);
        }
        out[((size_t)b * 128 + r) * 4 + cc] = val;
    } else if (tid < 512) {
        int j = tid - 256;
        out[((size_t)b * 128 + 64) * 4 + j] = 0.0f;   // TOTAL_NEG zero boxes
    } else if (tid < 576) {
        int r = tid - 512;
        outIdx[b * 64 + r] = (float)s_gtbest[s_selidx[r]];
    }
}

extern "C" void kernel_launch(void* const* d_in, const int* in_sizes, int n_in,
                              void* d_out, int out_size, void* d_ws, size_t ws_size,
                              hipStream_t stream) {
    const float* deltas  = (const float*)d_in[0];
    const float* labels  = (const float*)d_in[1];
    const float* anchors = (const float*)d_in[2];
    const float* gt      = (const float*)d_in[3];
    float* out = (float*)d_out;
    roi_bbox_kernel<<<NBATCH, 1024, 0, stream>>>(deltas, labels, anchors, gt, out);
}

// Round 5
// 164.557 us; speedup vs baseline: 1.2885x; 1.2885x over previous
//
#include <hip/hip_runtime.h>
#include <stdint.h>

#define N_ANCH 36864
#define KCAND  4096
#define NBUCK  384
#define NSEL   300
#define NGT    64
#define NBATCH 16
#define SCORE_THRESH 0.908f

typedef unsigned long long u64;

__device__ __forceinline__ float clip01(float v) { return fminf(fmaxf(v, 0.0f), 1.0f); }

// Exact decision "RN(inter/D) >= 0.5f" without division in the common case.
// D is computed in the reference's exact op order: ((aa+ab) - inter) + 1e-7f.
// Proof: q = RN(inter/D) >= 0.5  <=>  inter/D >= 0.5 - 2^-26 (tie rounds up to
// 0.5, which has an even mantissa).
//   hi:  inter >= 0.5*D (exact product)  =>  inter/D >= 0.5      => q >= 0.5.
//   lo:  r = RN(dt*(1-2^-23)) <= dt*(1-2^-24) < D*(0.5-2^-26);
//        inter < r  =>  inter/D < 0.5 - 2^-26  =>  q < 0.5.
// Band [r, dt): fall back to the actual IEEE division (prob ~2^-23 per pair).
__device__ __forceinline__ bool supp_pair(float ax, float ay, float az, float aw, float aa,
                                          const float4 B, float ab) {
    float y1 = fmaxf(ax, B.x);
    float x1 = fmaxf(ay, B.y);
    float y2 = fminf(az, B.z);
    float x2 = fminf(aw, B.w);
    float ih = fmaxf(y2 - y1, 0.0f);
    float iw = fmaxf(x2 - x1, 0.0f);
    float inter = ih * iw;
    float D  = ((aa + ab) - inter) + 1e-7f;   // exact reference op order
    float dt = 0.5f * D;                      // exact (no subnormals: D >= 1e-7)
    float r  = fmaf(dt, -0x1p-23f, dt);
    bool hi  = inter >= dt;                   // definitely q >= 0.5
    bool unc = (!hi) && (inter >= r);         // boundary band -> divide
    if (__builtin_expect(__any((int)unc), 0))
        return (inter / D) >= 0.5f;           // exact for every lane
    return hi;
}

__device__ __forceinline__ float4 decode_one(const float4 a4, const float4 d4) {
    float ah = a4.z - a4.x, aw = a4.w - a4.y;
    float acy = a4.x + 0.5f * ah, acx = a4.y + 0.5f * aw;
    float h = expf(d4.z) * ah, w = expf(d4.w) * aw;
    float cy = d4.x * ah + acy, cx = d4.y * aw + acx;
    float y1 = cy - 0.5f * h, x1 = cx - 0.5f * w;
    return make_float4(y1, x1, y1 + h, x1 + w);
}

// scores in (0.908, 1.0) all share exponent 0x7E -> ulp-linear bucket digit,
// ascending digit == descending score. width 4096 ulps -> lambda ~9 per bucket.
__device__ __forceinline__ int bucket_of(float s) {
    unsigned d = (0x3F800000u - __float_as_uint(s)) >> 12;
    return (d < NBUCK) ? (int)d : (NBUCK - 1);
}

__global__ __launch_bounds__(1024)
void roi_bbox_kernel(const float* __restrict__ deltas,
                     const float* __restrict__ labels,
                     const float* __restrict__ anchors,
                     const float* __restrict__ gt,
                     float* __restrict__ out)
{
    __shared__ u64    s_sorted[KCAND];   // 32 KB, bucket-ordered then rank-sorted
    __shared__ int    s_hist[NBUCK];
    __shared__ int    s_cur[NBUCK];
    __shared__ int    s_base[NBUCK + 1];
    __shared__ float4 s_accB[NSEL + 4];  // accepted raw (unclipped) boxes, pop order
    __shared__ float4 s_cbox[2][128];    // double-buffered PAIR boxes (128/pair)
    __shared__ unsigned int s_pre[2][128];   // suppression flags per candidate
    __shared__ unsigned int s_gmlo[2][128];  // intra-half 64-bit masks (lo)
    __shared__ unsigned int s_gmhi[2][128];  // intra-half 64-bit masks (hi)
    __shared__ int   s_accCount;
    __shared__ float s_merged[NSEL];
    __shared__ int   s_gtbest[NSEL];
    __shared__ float4 s_gt[NGT];
    __shared__ int   s_selidx[64];

    const int b    = blockIdx.x;
    const int tid  = threadIdx.x;
    const int lane = tid & 63;
    const int wv   = tid >> 6;
    const float*  sc    = labels + (size_t)b * N_ANCH;
    const float4* sc4   = (const float4*)sc;
    const float4* anch4 = (const float4*)(anchors + (size_t)b * N_ANCH * 4);
    const float4* del4  = (const float4*)(deltas  + (size_t)b * N_ANCH * 4);
    const float4* gt4   = (const float4*)(gt + (size_t)b * NGT * 4);

    if (tid < NBUCK) s_hist[tid] = 0;
    if (tid == 0) s_accCount = 0;
    __syncthreads();

    // ---- Phase A1: bucket histogram (float4-vectorized) ----
    for (int i = tid; i < N_ANCH / 4; i += 1024) {
        float4 v = sc4[i];
        float vv[4] = {v.x, v.y, v.z, v.w};
        #pragma unroll
        for (int k = 0; k < 4; ++k)
            if (vv[k] > SCORE_THRESH) atomicAdd(&s_hist[bucket_of(vv[k])], 1);
    }
    __syncthreads();

    // ---- exclusive scan of 384 counts (wave 0: 6 counts/lane + shfl scan) ----
    if (tid < 64) {
        int c[6]; int sum = 0;
        #pragma unroll
        for (int k = 0; k < 6; ++k) { c[k] = s_hist[tid * 6 + k]; sum += c[k]; }
        int inc = sum;
        #pragma unroll
        for (int off = 1; off < 64; off <<= 1) {
            int v = __shfl_up(inc, off);
            if (lane >= off) inc += v;
        }
        int excl = inc - sum;
        #pragma unroll
        for (int k = 0; k < 6; ++k) {
            s_base[tid * 6 + k] = excl;
            s_cur[tid * 6 + k]  = excl;
            excl += c[k];
        }
        if (tid == 63) s_base[NBUCK] = excl;
    }
    __syncthreads();

    // ---- Phase A2: scatter keys into bucket regions (L2-hot reload, vectorized) ----
    for (int i = tid; i < N_ANCH / 4; i += 1024) {
        float4 v = sc4[i];
        float vv[4] = {v.x, v.y, v.z, v.w};
        #pragma unroll
        for (int k = 0; k < 4; ++k) {
            float sval = vv[k];
            if (sval > SCORE_THRESH) {
                int idx = i * 4 + k;
                int pos = atomicAdd(&s_cur[bucket_of(sval)], 1);
                if (pos < KCAND)
                    s_sorted[pos] = ((u64)__float_as_uint(sval) << 32)
                                  | (u64)(0xFFFFFFFFu - (unsigned)idx);
            }
        }
    }
    __syncthreads();

    // ---- per-bucket rank sort (one wave per bucket, no barriers inside) ----
    for (int bk = wv; bk < NBUCK; bk += 16) {
        int lo = s_base[bk], hi = s_base[bk + 1];
        if (lo > KCAND) lo = KCAND;
        if (hi > KCAND) hi = KCAND;
        int n = hi - lo;
        if (n <= 1) continue;
        u64 mykey = (lane < n) ? s_sorted[lo + lane] : 0ull;
        int rank = 0;
        for (int j = 0; j < n; ++j) {          // broadcast reads, conflict-free
            u64 kj = s_sorted[lo + j];
            rank += (kj > mykey);
        }
        if (lane < n) s_sorted[lo + rank] = mykey;  // in-wave: reads precede write
    }
    __syncthreads();

    int M = s_base[NBUCK]; if (M > KCAND) M = KCAND;

    // ---- pre-loop: decode pair 0 (128 candidates), zero parity-0 masks ----
    if (tid < 128) {
        s_pre[0][tid] = 0u; s_gmlo[0][tid] = 0u; s_gmhi[0][tid] = 0u;
        if (tid < M) {
            u64 key = s_sorted[tid];
            int idx = (int)(0xFFFFFFFFu - (unsigned)(key & 0xFFFFFFFFull));
            s_cbox[0][tid] = decode_one(anch4[idx], del4[idx]);
        }
    }
    __syncthreads();

    // ---- Phase B: greedy NMS, 128-candidate pairs, R1-style 64-wide resolve ----
    // Per pair: P1 long-loop(both halves vs list@pairStart) + intra1 + intra2
    //           + next-pair decode; P2 resolve half1; P3 half2 vs new accepts;
    //           P4 resolve half2.  4 barriers / 128 cands (same rate as before).
    int accCount = 0;
    for (int start = 0; start < M && accCount < NSEL; start += 128) {
        int p  = (start >> 7) & 1;
        int C  = M - start; if (C > 128) C = 128;
        int C1 = C < 64 ? C : 64;
        int C2 = C - C1;                       // candidates in half2 (0..64)
        int c  = lane;
        int sidx15 = (wv == 0) ? 0 : (wv - 1); // 15-slice id for waves {0,2..15}

        float4 c0 = make_float4(0.f,0.f,0.f,0.f), c1 = make_float4(0.f,0.f,0.f,0.f);
        float a0 = 0.f, a1 = 0.f;

        // ---------------- P1 ----------------
        if (wv == 1) {
            // zero next pair's masks; decode next pair (2 boxes per lane)
            s_pre[p^1][c]       = 0u; s_pre[p^1][64+c]  = 0u;
            s_gmlo[p^1][c]      = 0u; s_gmlo[p^1][64+c] = 0u;
            s_gmhi[p^1][c]      = 0u; s_gmhi[p^1][64+c] = 0u;
            int ni0 = start + 128 + c;
            int ni1 = start + 192 + c;
            if (ni0 < M) {
                u64 key = s_sorted[ni0];
                int idx = (int)(0xFFFFFFFFu - (unsigned)(key & 0xFFFFFFFFull));
                s_cbox[p^1][c] = decode_one(anch4[idx], del4[idx]);
            }
            if (ni1 < M) {
                u64 key = s_sorted[ni1];
                int idx = (int)(0xFFFFFFFFu - (unsigned)(key & 0xFFFFFFFFull));
                s_cbox[p^1][64+c] = decode_one(anch4[idx], del4[idx]);
            }
        } else {
            // candidate registers (zero for invalid lanes: area 0 never matches,
            // never triggers the division fallback)
            if (c < C1) c0 = s_cbox[p][c];
            if (c < C2) c1 = s_cbox[p][64+c];
            a0 = (c0.z - c0.x) * (c0.w - c0.y);
            a1 = (c1.z - c1.x) * (c1.w - c1.y);

            // accepted-long-loop vs list at pair start: ONE read serves BOTH halves
            bool s0 = false, s1 = false;
            for (int a = sidx15; a < accCount; a += 15) {
                float4 A = s_accB[a];                       // broadcast b128
                float Aa = (A.z - A.x) * (A.w - A.y);       // recompute (VALU)
                s0 |= supp_pair(A.x, A.y, A.z, A.w, Aa, c0, a0);
                s1 |= supp_pair(A.x, A.y, A.z, A.w, Aa, c1, a1);
            }
            if (s0 && c < C1) atomicOr(&s_pre[p][c], 1u);
            if (s1 && c < C2) atomicOr(&s_pre[p][64+c], 1u);

            if (wv <= 8) {
                // intra half1: 8 slices (waves 0,2..8), j < c within [0,64)
                int s8 = sidx15;                 // 0..7
                if (c < C1) {
                    unsigned mlo = 0u, mhi = 0u;
                    for (int j = s8; j < c; j += 8) {
                        float4 bj = s_cbox[p][j];
                        float  aj = (bj.z - bj.x) * (bj.w - bj.y);
                        if (supp_pair(bj.x, bj.y, bj.z, bj.w, aj, c0, a0)) {
                            if (j < 32) mlo |= 1u << j; else mhi |= 1u << (j - 32);
                        }
                    }
                    if (mlo) atomicOr(&s_gmlo[p][c], mlo);
                    if (mhi) atomicOr(&s_gmhi[p][c], mhi);
                }
            } else {
                // intra half2: 7 slices (waves 9..15), jj < c within half2
                int s7 = wv - 9;                 // 0..6
                if (c < C2) {
                    unsigned mlo = 0u, mhi = 0u;
                    for (int jj = s7; jj < c; jj += 7) {
                        float4 bj = s_cbox[p][64+jj];
                        float  aj = (bj.z - bj.x) * (bj.w - bj.y);
                        if (supp_pair(bj.x, bj.y, bj.z, bj.w, aj, c1, a1)) {
                            if (jj < 32) mlo |= 1u << jj; else mhi |= 1u << (jj - 32);
                        }
                    }
                    if (mlo) atomicOr(&s_gmlo[p][64+c], mlo);
                    if (mhi) atomicOr(&s_gmhi[p][64+c], mhi);
                }
            }
        }
        __syncthreads();

        // ---------------- P2: resolve half1 (wave 0) ----------------
        if (tid < 64) {
            u64 mymask = ((u64)s_gmhi[p][tid] << 32) | (u64)s_gmlo[p][tid];
            bool alive = (tid < C1) && (s_pre[p][tid] == 0u);
            u64 accbits = 0ull, done = 0ull;
            int room = NSEL - accCount;
            int na = 0;
            while (na < room) {
                u64 am  = __ballot(alive);
                u64 rem = am & ~done;
                if (!rem) break;
                int l = __ffsll(rem) - 1;
                done = (2ull << l) - 1ull;
                accbits |= (1ull << l);
                ++na;
                if ((mymask >> l) & 1ull) alive = false;
            }
            if ((accbits >> tid) & 1ull) {
                int rank = __popcll(accbits & ((1ull << tid) - 1ull));
                s_accB[accCount + rank] = s_cbox[p][tid];
            }
            if (tid == 0) s_accCount = accCount + __popcll(accbits);
        }
        __syncthreads();
        int acc1 = s_accCount;

        // ---------------- P3: half2 vs half1's new accepts ----------------
        if (wv != 1) {
            bool s1 = false;
            for (int a = accCount + sidx15; a < acc1; a += 15) {
                float4 A = s_accB[a];
                float Aa = (A.z - A.x) * (A.w - A.y);
                s1 |= supp_pair(A.x, A.y, A.z, A.w, Aa, c1, a1);
            }
            if (s1 && c < C2) atomicOr(&s_pre[p][64+c], 1u);
        }
        __syncthreads();

        // ---------------- P4: resolve half2 (wave 0) ----------------
        if (tid < 64) {
            u64 mymask = ((u64)s_gmhi[p][64+tid] << 32) | (u64)s_gmlo[p][64+tid];
            bool alive = (tid < C2) && (s_pre[p][64+tid] == 0u);
            u64 accbits = 0ull, done = 0ull;
            int room = NSEL - acc1;
            int na = 0;
            while (na < room) {
                u64 am  = __ballot(alive);
                u64 rem = am & ~done;
                if (!rem) break;
                int l = __ffsll(rem) - 1;
                done = (2ull << l) - 1ull;
                accbits |= (1ull << l);
                ++na;
                if ((mymask >> l) & 1ull) alive = false;
            }
            if ((accbits >> tid) & 1ull) {
                int rank = __popcll(accbits & ((1ull << tid) - 1ull));
                s_accB[acc1 + rank] = s_cbox[p][64+tid];
            }
            if (tid == 0) s_accCount = acc1 + __popcll(accbits);
        }
        __syncthreads();
        accCount = s_accCount;
    }

    // ---- Phase C: select_rois ----
    if (tid < NGT) s_gt[tid] = gt4[tid];
    __syncthreads();

    if (tid < NSEL) {
        float4 bx;
        if (tid < accCount) {
            float4 r = s_accB[tid];
            bx = make_float4(clip01(r.x), clip01(r.y), clip01(r.z), clip01(r.w));
        } else bx = make_float4(0.f, 0.f, 0.f, 0.f);
        float aa = (bx.z - bx.x) * (bx.w - bx.y);
        float best = -1e38f; int bi = 0;
        for (int g = 0; g < NGT; ++g) {
            float4 gb = s_gt[g];
            float y1 = fmaxf(bx.x, gb.x);
            float x1 = fmaxf(bx.y, gb.y);
            float y2 = fminf(bx.z, gb.z);
            float x2 = fminf(bx.w, gb.w);
            float ih = fmaxf(y2 - y1, 0.0f);
            float iw = fmaxf(x2 - x1, 0.0f);
            float inter = ih * iw;
            float ab = (gb.z - gb.x) * (gb.w - gb.y);
            float iou = inter / (aa + ab - inter + 1e-7f);
            if (iou > best) { best = iou; bi = g; }   // first-occurrence argmax
        }
        s_merged[tid] = best;
        s_gtbest[tid] = bi;
    }
    __syncthreads();

    // stable top-64 via rank selection: rank = #{j: v_j > v_i || (v_j==v_i && j<i)}
    if (tid < NSEL) {
        float v = s_merged[tid];
        int rank = 0;
        for (int j = 0; j < NSEL; ++j) {
            float u = s_merged[j];
            rank += (u > v) || (u == v && j < tid);
        }
        if (rank < 64) s_selidx[rank] = tid;
    }
    __syncthreads();

    // ---- outputs ----
    float* outIdx = out + (size_t)NBATCH * 128 * 4;   // 8192 box floats first
    if (tid < 256) {
        int r = tid >> 2, cc = tid & 3;
        int i = s_selidx[r];
        float val = 0.0f;
        if (i < accCount) {
            const float* p = (const float*)&s_accB[i];
            val = clip01(p[cc]);
        }
        out[((size_t)b * 128 + r) * 4 + cc] = val;
    } else if (tid < 512) {
        int j = tid - 256;
        out[((size_t)b * 128 + 64) * 4 + j] = 0.0f;   // TOTAL_NEG zero boxes
    } else if (tid < 576) {
        int r = tid - 512;
        outIdx[b * 64 + r] = (float)s_gtbest[s_selidx[r]];
    }
}

extern "C" void kernel_launch(void* const* d_in, const int* in_sizes, int n_in,
                              void* d_out, int out_size, void* d_ws, size_t ws_size,
                              hipStream_t stream) {
    const float* deltas  = (const float*)d_in[0];
    const float* labels  = (const float*)d_in[1];
    const float* anchors = (const float*)d_in[2];
    const float* gt      = (const float*)d_in[3];
    float* out = (float*)d_out;
    roi_bbox_kernel<<<NBATCH, 1024, 0, stream>>>(deltas, labels, anchors, gt, out);
}

// Round 6
// 159.777 us; speedup vs baseline: 1.3270x; 1.0299x over previous
//
#include <hip/hip_runtime.h>
#include <stdint.h>

#define N_ANCH 36864
#define KCAND  4096
#define NBUCK  384
#define NSEL   300
#define NGT    64
#define NBATCH 16
#define SCORE_THRESH 0.908f

typedef unsigned long long u64;

__device__ __forceinline__ float clip01(float v) { return fminf(fmaxf(v, 0.0f), 1.0f); }

// ---- Exact division-free suppression, branchless accumulation form ----
// Reference decision: RN(inter / D) >= 0.5, D = ((aa+ab) - inter) + 1e-7f.
//   dt = 0.5*D (exact),  r = RN(dt*(1-2^-23)) < dt.
//   inter >= dt  => q >= 0.5 certainly;  inter < r => q < 0.5 certainly;
//   inter in [r, dt) -> uncertain band (width ~1 ulp) -> exact division rerun.
// Sign-exact trick: RN(inter - dt) has the sign of the exact difference
// (Sterbenz exactness for dt/2<=inter<=2dt; big gaps keep sign; x-x=+0, and
// -0 never arises from RN subtraction), so
//   m  = max over pairs of (inter - dt)  =>  m  >= 0  <=> exists certain-suppress
//   mm = max over pairs of (inter - r)   =>  mm >= 0 && m < 0 <=> uncertain only
// One __any over (m<0 && mm>=0) AFTER the loop; loop body is branch-free.
__device__ __forceinline__ void supp_acc(const float4 A, float Aa, const float4 B, float ab,
                                         float& m, float& mm) {
    float y1 = fmaxf(A.x, B.x);
    float x1 = fmaxf(A.y, B.y);
    float y2 = fminf(A.z, B.z);
    float x2 = fminf(A.w, B.w);
    float ih = fmaxf(y2 - y1, 0.0f);
    float iw = fmaxf(x2 - x1, 0.0f);
    float inter = ih * iw;
    float D  = ((Aa + ab) - inter) + 1e-7f;   // exact reference op order
    float dt = 0.5f * D;                      // exact (D >= 1e-7, no subnormals)
    float r  = fmaf(dt, -0x1p-23f, dt);
    m  = fmaxf(m,  inter - dt);
    mm = fmaxf(mm, inter - r);
}

__device__ __forceinline__ bool supp_div(const float4 A, float Aa, const float4 B, float ab) {
    float y1 = fmaxf(A.x, B.x);
    float x1 = fmaxf(A.y, B.y);
    float y2 = fminf(A.z, B.z);
    float x2 = fminf(A.w, B.w);
    float ih = fmaxf(y2 - y1, 0.0f);
    float iw = fmaxf(x2 - x1, 0.0f);
    float inter = ih * iw;
    float D = ((Aa + ab) - inter) + 1e-7f;
    return (inter / D) >= 0.5f;               // exact IEEE decision
}

// single test with certain flag + uncertain flag (for intra-chunk bit masks)
__device__ __forceinline__ void supp_bit(const float4 A, float Aa, const float4 B, float ab,
                                         bool& sj, bool& uj) {
    float y1 = fmaxf(A.x, B.x);
    float x1 = fmaxf(A.y, B.y);
    float y2 = fminf(A.z, B.z);
    float x2 = fminf(A.w, B.w);
    float ih = fmaxf(y2 - y1, 0.0f);
    float iw = fmaxf(x2 - x1, 0.0f);
    float inter = ih * iw;
    float D  = ((Aa + ab) - inter) + 1e-7f;
    float dt = 0.5f * D;
    float r  = fmaf(dt, -0x1p-23f, dt);
    sj = inter >= dt;
    uj = (inter >= r) && !sj;
}

__device__ __forceinline__ float4 decode_one(const float4 a4, const float4 d4) {
    float ah = a4.z - a4.x, aw = a4.w - a4.y;
    float acy = a4.x + 0.5f * ah, acx = a4.y + 0.5f * aw;
    float h = expf(d4.z) * ah, w = expf(d4.w) * aw;
    float cy = d4.x * ah + acy, cx = d4.y * aw + acx;
    float y1 = cy - 0.5f * h, x1 = cx - 0.5f * w;
    return make_float4(y1, x1, y1 + h, x1 + w);
}

// scores in (0.908, 1.0) all share exponent 0x7E -> ulp-linear bucket digit,
// ascending digit == descending score. width 4096 ulps -> lambda ~9 per bucket.
__device__ __forceinline__ int bucket_of(float s) {
    unsigned d = (0x3F800000u - __float_as_uint(s)) >> 12;
    return (d < NBUCK) ? (int)d : (NBUCK - 1);
}

__global__ __launch_bounds__(1024)
void roi_bbox_kernel(const float* __restrict__ deltas,
                     const float* __restrict__ labels,
                     const float* __restrict__ anchors,
                     const float* __restrict__ gt,
                     float* __restrict__ out)
{
    __shared__ u64    s_sorted[KCAND];   // 32 KB, bucket-ordered then rank-sorted
    __shared__ int    s_hist[NBUCK];
    __shared__ int    s_cur[NBUCK];
    __shared__ int    s_base[NBUCK + 1];
    __shared__ float4 s_accB[NSEL + 4];  // accepted raw (unclipped) boxes, pop order
    __shared__ float4 s_cbox[2][128];    // double-buffered PAIR boxes (128/pair)
    __shared__ unsigned int s_pre[2][128];   // suppression flags per candidate
    __shared__ unsigned int s_gmlo[2][128];  // intra-half 64-bit masks (lo)
    __shared__ unsigned int s_gmhi[2][128];  // intra-half 64-bit masks (hi)
    __shared__ int   s_accCount;
    __shared__ float s_merged[NSEL];
    __shared__ int   s_gtbest[NSEL];
    __shared__ float4 s_gt[NGT];
    __shared__ int   s_selidx[64];

    const int b    = blockIdx.x;
    const int tid  = threadIdx.x;
    const int lane = tid & 63;
    const int wv   = tid >> 6;
    const float*  sc    = labels + (size_t)b * N_ANCH;
    const float4* sc4   = (const float4*)sc;
    const float4* anch4 = (const float4*)(anchors + (size_t)b * N_ANCH * 4);
    const float4* del4  = (const float4*)(deltas  + (size_t)b * N_ANCH * 4);
    const float4* gt4   = (const float4*)(gt + (size_t)b * NGT * 4);

    if (tid < NBUCK) s_hist[tid] = 0;
    if (tid == 0) s_accCount = 0;
    __syncthreads();

    // ---- Phase A1: bucket histogram (float4-vectorized) ----
    for (int i = tid; i < N_ANCH / 4; i += 1024) {
        float4 v = sc4[i];
        float vv[4] = {v.x, v.y, v.z, v.w};
        #pragma unroll
        for (int k = 0; k < 4; ++k)
            if (vv[k] > SCORE_THRESH) atomicAdd(&s_hist[bucket_of(vv[k])], 1);
    }
    __syncthreads();

    // ---- exclusive scan of 384 counts (wave 0: 6 counts/lane + shfl scan) ----
    if (tid < 64) {
        int c[6]; int sum = 0;
        #pragma unroll
        for (int k = 0; k < 6; ++k) { c[k] = s_hist[tid * 6 + k]; sum += c[k]; }
        int inc = sum;
        #pragma unroll
        for (int off = 1; off < 64; off <<= 1) {
            int v = __shfl_up(inc, off);
            if (lane >= off) inc += v;
        }
        int excl = inc - sum;
        #pragma unroll
        for (int k = 0; k < 6; ++k) {
            s_base[tid * 6 + k] = excl;
            s_cur[tid * 6 + k]  = excl;
            excl += c[k];
        }
        if (tid == 63) s_base[NBUCK] = excl;
    }
    __syncthreads();

    // ---- Phase A2: scatter keys into bucket regions (L2-hot reload, vectorized) ----
    for (int i = tid; i < N_ANCH / 4; i += 1024) {
        float4 v = sc4[i];
        float vv[4] = {v.x, v.y, v.z, v.w};
        #pragma unroll
        for (int k = 0; k < 4; ++k) {
            float sval = vv[k];
            if (sval > SCORE_THRESH) {
                int idx = i * 4 + k;
                int pos = atomicAdd(&s_cur[bucket_of(sval)], 1);
                if (pos < KCAND)
                    s_sorted[pos] = ((u64)__float_as_uint(sval) << 32)
                                  | (u64)(0xFFFFFFFFu - (unsigned)idx);
            }
        }
    }
    __syncthreads();

    // ---- per-bucket rank sort (one wave per bucket, no barriers inside) ----
    for (int bk = wv; bk < NBUCK; bk += 16) {
        int lo = s_base[bk], hi = s_base[bk + 1];
        if (lo > KCAND) lo = KCAND;
        if (hi > KCAND) hi = KCAND;
        int n = hi - lo;
        if (n <= 1) continue;
        u64 mykey = (lane < n) ? s_sorted[lo + lane] : 0ull;
        int rank = 0;
        for (int j = 0; j < n; ++j) {          // broadcast reads, conflict-free
            u64 kj = s_sorted[lo + j];
            rank += (kj > mykey);
        }
        if (lane < n) s_sorted[lo + rank] = mykey;  // in-wave: reads precede write
    }
    __syncthreads();

    int M = s_base[NBUCK]; if (M > KCAND) M = KCAND;

    // ---- pre-loop: decode pair 0 (128 candidates), zero parity-0 masks ----
    if (tid < 128) {
        s_pre[0][tid] = 0u; s_gmlo[0][tid] = 0u; s_gmhi[0][tid] = 0u;
        if (tid < M) {
            u64 key = s_sorted[tid];
            int idx = (int)(0xFFFFFFFFu - (unsigned)(key & 0xFFFFFFFFull));
            s_cbox[0][tid] = decode_one(anch4[idx], del4[idx]);
        }
    }
    __syncthreads();

    // ---- Phase B: greedy NMS, 128-candidate pairs ----
    // R1: wv1 decode/zero; others long-loop both halves (branchless, unroll x2);
    //     waves 2..9 intra-half1.   bar
    // R2: wave0 resolve half1 || waves 9..15 intra-half2.   bar
    // R3: half2 vs new accepts (15 slices).   bar
    // R4: wave0 resolve half2.   bar
    int accCount = 0;
    for (int start = 0; start < M && accCount < NSEL; start += 128) {
        int p  = (start >> 7) & 1;
        int C  = M - start; if (C > 128) C = 128;
        int C1 = C < 64 ? C : 64;
        int C2 = C - C1;                       // candidates in half2 (0..64)
        int c  = lane;
        int sidx15 = (wv == 0) ? 0 : (wv - 1); // 15-slice id for waves {0,2..15}

        float4 c0 = make_float4(0.f,0.f,0.f,0.f), c1 = make_float4(0.f,0.f,0.f,0.f);
        float a0 = 0.f, a1 = 0.f;

        // ---------------- Region 1 ----------------
        if (wv == 1) {
            s_pre[p^1][c]       = 0u; s_pre[p^1][64+c]  = 0u;
            s_gmlo[p^1][c]      = 0u; s_gmlo[p^1][64+c] = 0u;
            s_gmhi[p^1][c]      = 0u; s_gmhi[p^1][64+c] = 0u;
            int ni0 = start + 128 + c;
            int ni1 = start + 192 + c;
            if (ni0 < M) {
                u64 key = s_sorted[ni0];
                int idx = (int)(0xFFFFFFFFu - (unsigned)(key & 0xFFFFFFFFull));
                s_cbox[p^1][c] = decode_one(anch4[idx], del4[idx]);
            }
            if (ni1 < M) {
                u64 key = s_sorted[ni1];
                int idx = (int)(0xFFFFFFFFu - (unsigned)(key & 0xFFFFFFFFull));
                s_cbox[p^1][64+c] = decode_one(anch4[idx], del4[idx]);
            }
        } else {
            // candidate registers (zero-box for invalid lanes: inter==0 always,
            // never suppressed, never triggers the uncertain band)
            if (c < C1) c0 = s_cbox[p][c];
            if (c < C2) c1 = s_cbox[p][64+c];
            a0 = (c0.z - c0.x) * (c0.w - c0.y);
            a1 = (c1.z - c1.x) * (c1.w - c1.y);

            // branchless long-loop, unroll x2 accepted: 2 loads + 4 indep chains
            float m0 = -1.f, mm0 = -1.f, m1 = -1.f, mm1 = -1.f;
            int a = sidx15;
            for (; a + 15 < accCount; a += 30) {
                float4 A0 = s_accB[a];
                float4 A1 = s_accB[a + 15];
                float Aa0 = (A0.z - A0.x) * (A0.w - A0.y);
                float Aa1 = (A1.z - A1.x) * (A1.w - A1.y);
                supp_acc(A0, Aa0, c0, a0, m0, mm0);
                supp_acc(A0, Aa0, c1, a1, m1, mm1);
                supp_acc(A1, Aa1, c0, a0, m0, mm0);
                supp_acc(A1, Aa1, c1, a1, m1, mm1);
            }
            if (a < accCount) {
                float4 A0 = s_accB[a];
                float Aa0 = (A0.z - A0.x) * (A0.w - A0.y);
                supp_acc(A0, Aa0, c0, a0, m0, mm0);
                supp_acc(A0, Aa0, c1, a1, m1, mm1);
            }
            bool s0 = (m0 >= 0.f), s1 = (m1 >= 0.f);
            bool rr = ((m0 < 0.f) && (mm0 >= 0.f)) || ((m1 < 0.f) && (mm1 >= 0.f));
            if (__builtin_expect(__any((int)rr), 0)) {
                for (int a2 = sidx15; a2 < accCount; a2 += 15) {
                    float4 A = s_accB[a2];
                    float Aa = (A.z - A.x) * (A.w - A.y);
                    s0 |= supp_div(A, Aa, c0, a0);
                    s1 |= supp_div(A, Aa, c1, a1);
                }
            }
            if (s0 && c < C1) s_pre[p][c]      = 1u;   // same-value race, benign
            if (s1 && c < C2) s_pre[p][64 + c] = 1u;

            // intra half1: waves 2..9, 8 slices, branchless + deferred rerun
            if (wv >= 2 && wv <= 9 && c < C1) {
                int s8 = wv - 2;
                unsigned mlo = 0u, mhi = 0u;
                bool ur = false;
                for (int j = s8; j < c; j += 8) {        // j wave-uniform
                    float4 bj = s_cbox[p][j];
                    float  aj = (bj.z - bj.x) * (bj.w - bj.y);
                    bool sj, uj;
                    supp_bit(bj, aj, c0, a0, sj, uj);
                    ur |= uj;
                    unsigned bit = sj ? 1u : 0u;
                    if (j < 32) mlo |= bit << j; else mhi |= bit << (j - 32);
                }
                if (__builtin_expect(__any((int)ur), 0)) {
                    for (int j = s8; j < c; j += 8) {
                        float4 bj = s_cbox[p][j];
                        float  aj = (bj.z - bj.x) * (bj.w - bj.y);
                        unsigned bit = supp_div(bj, aj, c0, a0) ? 1u : 0u;
                        if (j < 32) mlo |= bit << j; else mhi |= bit << (j - 32);
                    }
                }
                if (mlo) atomicOr(&s_gmlo[p][c], mlo);
                if (mhi) atomicOr(&s_gmhi[p][c], mhi);
            }
        }
        __syncthreads();

        // ---------------- Region 2: resolve half1 || intra half2 ----------------
        if (tid < 64) {
            u64 mymask = ((u64)s_gmhi[p][tid] << 32) | (u64)s_gmlo[p][tid];
            bool alive = (tid < C1) && (s_pre[p][tid] == 0u);
            u64 accbits = 0ull, done = 0ull;
            int room = NSEL - accCount;
            int na = 0;
            while (na < room) {
                u64 am  = __ballot(alive);
                u64 rem = am & ~done;
                if (!rem) break;
                int l = __ffsll(rem) - 1;
                done = (2ull << l) - 1ull;
                accbits |= (1ull << l);
                ++na;
                if ((mymask >> l) & 1ull) alive = false;
            }
            if ((accbits >> tid) & 1ull) {
                int rank = __popcll(accbits & ((1ull << tid) - 1ull));
                s_accB[accCount + rank] = s_cbox[p][tid];
            }
            if (tid == 0) s_accCount = accCount + __popcll(accbits);
        } else if (wv >= 9 && c < C2) {
            // intra half2: waves 9..15, 7 slices (overlaps the serial resolve)
            int s7 = wv - 9;
            unsigned mlo = 0u, mhi = 0u;
            bool ur = false;
            for (int jj = s7; jj < c; jj += 7) {
                float4 bj = s_cbox[p][64 + jj];
                float  aj = (bj.z - bj.x) * (bj.w - bj.y);
                bool sj, uj;
                supp_bit(bj, aj, c1, a1, sj, uj);
                ur |= uj;
                unsigned bit = sj ? 1u : 0u;
                if (jj < 32) mlo |= bit << jj; else mhi |= bit << (jj - 32);
            }
            if (__builtin_expect(__any((int)ur), 0)) {
                for (int jj = s7; jj < c; jj += 7) {
                    float4 bj = s_cbox[p][64 + jj];
                    float  aj = (bj.z - bj.x) * (bj.w - bj.y);
                    unsigned bit = supp_div(bj, aj, c1, a1) ? 1u : 0u;
                    if (jj < 32) mlo |= bit << jj; else mhi |= bit << (jj - 32);
                }
            }
            if (mlo) atomicOr(&s_gmlo[p][64 + c], mlo);
            if (mhi) atomicOr(&s_gmhi[p][64 + c], mhi);
        }
        __syncthreads();
        int acc1 = s_accCount;

        // ---------------- Region 3: half2 vs half1's new accepts ----------------
        if (wv != 1) {
            float m1b = -1.f, mm1b = -1.f;
            for (int a3 = accCount + sidx15; a3 < acc1; a3 += 15) {
                float4 A = s_accB[a3];
                float Aa = (A.z - A.x) * (A.w - A.y);
                supp_acc(A, Aa, c1, a1, m1b, mm1b);
            }
            bool s1b = (m1b >= 0.f);
            bool rr  = (m1b < 0.f) && (mm1b >= 0.f);
            if (__builtin_expect(__any((int)rr), 0)) {
                for (int a3 = accCount + sidx15; a3 < acc1; a3 += 15) {
                    float4 A = s_accB[a3];
                    float Aa = (A.z - A.x) * (A.w - A.y);
                    s1b |= supp_div(A, Aa, c1, a1);
                }
            }
            if (s1b && c < C2) s_pre[p][64 + c] = 1u;
        }
        __syncthreads();

        // ---------------- Region 4: resolve half2 ----------------
        if (tid < 64) {
            u64 mymask = ((u64)s_gmhi[p][64+tid] << 32) | (u64)s_gmlo[p][64+tid];
            bool alive = (tid < C2) && (s_pre[p][64+tid] == 0u);
            u64 accbits = 0ull, done = 0ull;
            int room = NSEL - acc1;
            int na = 0;
            while (na < room) {
                u64 am  = __ballot(alive);
                u64 rem = am & ~done;
                if (!rem) break;
                int l = __ffsll(rem) - 1;
                done = (2ull << l) - 1ull;
                accbits |= (1ull << l);
                ++na;
                if ((mymask >> l) & 1ull) alive = false;
            }
            if ((accbits >> tid) & 1ull) {
                int rank = __popcll(accbits & ((1ull << tid) - 1ull));
                s_accB[acc1 + rank] = s_cbox[p][64+tid];
            }
            if (tid == 0) s_accCount = acc1 + __popcll(accbits);
        }
        __syncthreads();
        accCount = s_accCount;
    }

    // ---- Phase C: select_rois ----
    if (tid < NGT) s_gt[tid] = gt4[tid];
    __syncthreads();

    if (tid < NSEL) {
        float4 bx;
        if (tid < accCount) {
            float4 r = s_accB[tid];
            bx = make_float4(clip01(r.x), clip01(r.y), clip01(r.z), clip01(r.w));
        } else bx = make_float4(0.f, 0.f, 0.f, 0.f);
        float aa = (bx.z - bx.x) * (bx.w - bx.y);
        float best = -1e38f; int bi = 0;
        for (int g = 0; g < NGT; ++g) {
            float4 gb = s_gt[g];
            float y1 = fmaxf(bx.x, gb.x);
            float x1 = fmaxf(bx.y, gb.y);
            float y2 = fminf(bx.z, gb.z);
            float x2 = fminf(bx.w, gb.w);
            float ih = fmaxf(y2 - y1, 0.0f);
            float iw = fmaxf(x2 - x1, 0.0f);
            float inter = ih * iw;
            float ab = (gb.z - gb.x) * (gb.w - gb.y);
            float iou = inter / (aa + ab - inter + 1e-7f);
            if (iou > best) { best = iou; bi = g; }   // first-occurrence argmax
        }
        s_merged[tid] = best;
        s_gtbest[tid] = bi;
    }
    __syncthreads();

    // stable top-64 via rank selection: rank = #{j: v_j > v_i || (v_j==v_i && j<i)}
    if (tid < NSEL) {
        float v = s_merged[tid];
        int rank = 0;
        for (int j = 0; j < NSEL; ++j) {
            float u = s_merged[j];
            rank += (u > v) || (u == v && j < tid);
        }
        if (rank < 64) s_selidx[rank] = tid;
    }
    __syncthreads();

    // ---- outputs ----
    float* outIdx = out + (size_t)NBATCH * 128 * 4;   // 8192 box floats first
    if (tid < 256) {
        int r = tid >> 2, cc = tid & 3;
        int i = s_selidx[r];
        float val = 0.0f;
        if (i < accCount) {
            const float* p = (const float*)&s_accB[i];
            val = clip01(p[cc]);
        }
        out[((size_t)b * 128 + r) * 4 + cc] = val;
    } else if (tid < 512) {
        int j = tid - 256;
        out[((size_t)b * 128 + 64) * 4 + j] = 0.0f;   // TOTAL_NEG zero boxes
    } else if (tid < 576) {
        int r = tid - 512;
        outIdx[b * 64 + r] = (float)s_gtbest[s_selidx[r]];
    }
}

extern "C" void kernel_launch(void* const* d_in, const int* in_sizes, int n_in,
                              void* d_out, int out_size, void* d_ws, size_t ws_size,
                              hipStream_t stream) {
    const float* deltas  = (const float*)d_in[0];
    const float* labels  = (const float*)d_in[1];
    const float* anchors = (const float*)d_in[2];
    const float* gt      = (const float*)d_in[3];
    float* out = (float*)d_out;
    roi_bbox_kernel<<<NBATCH, 1024, 0, stream>>>(deltas, labels, anchors, gt, out);
}